// Round 5
// baseline (398.959 us; speedup 1.0000x reference)
//
#include <hip/hip_runtime.h>
#include <hip/hip_bf16.h>
#include <hip/hip_cooperative_groups.h>

namespace cg = cooperative_groups;

#define DI 4096
#define DM 2048
#define NS 128
#define BB 128
#define NTHREADS 256

typedef __attribute__((ext_vector_type(8))) short bf16x8;
typedef __attribute__((ext_vector_type(4))) float f32x4;

__device__ __forceinline__ unsigned short f2bf(float f) {
  union { __hip_bfloat16 h; unsigned short u; } c;
  c.h = __float2bfloat16(f);
  return c.u;
}

// ---------------- GEMM phase body (R1-proven) ----------------
// C[b][n] = sum_k X[b][k]*W[n][k]; K split NSPLIT ways into partials.
// Per-block tile M=128 x N=32, K-step 32. 4 waves as 2(M) x 2(N).
template<int N, int K, int NSPLIT>
__device__ __forceinline__ void gemm_phase(
    const float* __restrict__ Xg, const float* __restrict__ Wg,
    float* part, __hip_bfloat16 (*As)[40], __hip_bfloat16 (*Bs)[40],
    int bid, int tid) {
  constexpr int NBLKS = N / 32;
  constexpr int KS = K / NSPLIT;
  constexpr int NSTEPS = KS / 32;
  const int nblk = bid % NBLKS;
  const int ks   = bid / NBLKS;
  const int kbase = ks * KS;
  const int lane = tid & 63;
  const int wid = tid >> 6;
  const int wr = wid & 1;
  const int wc = wid >> 1;
  const int r16 = lane & 15;
  const int kb = lane >> 4;

  const int arow = tid >> 3;
  const int seg  = tid & 7;

  f32x4 acc[4] = { {0,0,0,0}, {0,0,0,0}, {0,0,0,0}, {0,0,0,0} };

  const float* aG = Xg + (size_t)arow * K + kbase + seg * 4;
  const float* bG = Wg + (size_t)(nblk * 32 + arow) * K + kbase + seg * 4;

  float4 pa0 = *(const float4*)(aG + 0 * 32 * K);
  float4 pa1 = *(const float4*)(aG + 1 * 32 * K);
  float4 pa2 = *(const float4*)(aG + 2 * 32 * K);
  float4 pa3 = *(const float4*)(aG + 3 * 32 * K);
  float4 pb  = *(const float4*)(bG);

  for (int step = 0; step < NSTEPS; ++step) {
    if (step) __syncthreads();
    {
      ushort4 h;
      h.x = f2bf(pa0.x); h.y = f2bf(pa0.y); h.z = f2bf(pa0.z); h.w = f2bf(pa0.w);
      *(ushort4*)&As[arow +  0][seg * 4] = h;
      h.x = f2bf(pa1.x); h.y = f2bf(pa1.y); h.z = f2bf(pa1.z); h.w = f2bf(pa1.w);
      *(ushort4*)&As[arow + 32][seg * 4] = h;
      h.x = f2bf(pa2.x); h.y = f2bf(pa2.y); h.z = f2bf(pa2.z); h.w = f2bf(pa2.w);
      *(ushort4*)&As[arow + 64][seg * 4] = h;
      h.x = f2bf(pa3.x); h.y = f2bf(pa3.y); h.z = f2bf(pa3.z); h.w = f2bf(pa3.w);
      *(ushort4*)&As[arow + 96][seg * 4] = h;
      h.x = f2bf(pb.x);  h.y = f2bf(pb.y);  h.z = f2bf(pb.z);  h.w = f2bf(pb.w);
      *(ushort4*)&Bs[arow][seg * 4] = h;
    }
    if (step + 1 < NSTEPS) {
      const int o = (step + 1) * 32;
      pa0 = *(const float4*)(aG + o + 0 * 32 * K);
      pa1 = *(const float4*)(aG + o + 1 * 32 * K);
      pa2 = *(const float4*)(aG + o + 2 * 32 * K);
      pa3 = *(const float4*)(aG + o + 3 * 32 * K);
      pb  = *(const float4*)(bG + o);
    }
    __syncthreads();
    bf16x8 bv = *(const bf16x8*)&Bs[wc * 16 + r16][kb * 8];
#pragma unroll
    for (int m = 0; m < 4; ++m) {
      bf16x8 av = *(const bf16x8*)&As[wr * 64 + m * 16 + r16][kb * 8];
      acc[m] = __builtin_amdgcn_mfma_f32_16x16x32_bf16(av, bv, acc[m], 0, 0, 0);
    }
  }

  // C/D layout: col = lane&15, row = (lane>>4)*4 + reg
  const int ncol = nblk * 32 + wc * 16 + r16;
#pragma unroll
  for (int m = 0; m < 4; ++m) {
#pragma unroll
    for (int r = 0; r < 4; ++r) {
      int brow = wr * 64 + m * 16 + kb * 4 + r;
      part[(size_t)(ks * 128 + brow) * N + ncol] = acc[m][r];
    }
  }
}

// ---------------- Fused cooperative kernel ----------------
__global__ __launch_bounds__(256, 2) void fused_all(
    const float* x_t, const float* conv_state, const float* ssm,
    const float* W_in, const float* b_in, const float* conv_weight,
    const float* A, const float* Bp, const float* Cp, const float* Dp,
    const float* W_out, const float* b_out,
    float* y_t, float* ncs, float* nss,
    float* part1, float* part2, float* u_ws, float* y_in, float* dAe) {
  __shared__ __hip_bfloat16 As[128][40];
  __shared__ __hip_bfloat16 Bs[32][40];
  const int bid = blockIdx.x;
  const int tid = threadIdx.x;
  cg::grid_group grid = cg::this_grid();

  // Phase 1: GEMM1 (x_t @ W_in[:DI].T) -> part1, NSPLIT=4 (128 nblk x 4 ks)
  gemm_phase<DI, DM, 4>(x_t, W_in, part1, As, Bs, bid, tid);
  grid.sync();

  // Phase 2: combine1 (partial sum + bias -> conv + silu -> u, ncs) + dA=exp(A)
  {
    const int t = bid * NTHREADS + tid;            // 0..131071
    const size_t idx = (size_t)t * 4;              // 524288 elems
    const int d0 = (int)(idx & (DI - 1));
    f32x4 xp = *(const f32x4*)(b_in + d0);
#pragma unroll
    for (int s = 0; s < 4; ++s) {
      f32x4 p = *(const f32x4*)(part1 + (size_t)s * (BB * DI) + idx);
      xp[0] += p[0]; xp[1] += p[1]; xp[2] += p[2]; xp[3] += p[3];
    }
    const float* cs = conv_state + idx * 3;
    f32x4 cv0 = *(const f32x4*)(cs);
    f32x4 cv1 = *(const f32x4*)(cs + 4);
    f32x4 cv2 = *(const f32x4*)(cs + 8);
    float4 w0 = *(const float4*)(conv_weight + (size_t)(d0 + 0) * 4);
    float4 w1 = *(const float4*)(conv_weight + (size_t)(d0 + 1) * 4);
    float4 w2 = *(const float4*)(conv_weight + (size_t)(d0 + 2) * 4);
    float4 w3 = *(const float4*)(conv_weight + (size_t)(d0 + 3) * 4);
    float sv0 = cv0[0]*w0.x + cv0[1]*w0.y + cv0[2]*w0.z + xp[0]*w0.w;
    float sv1 = cv0[3]*w1.x + cv1[0]*w1.y + cv1[1]*w1.z + xp[1]*w1.w;
    float sv2 = cv1[2]*w2.x + cv1[3]*w2.y + cv2[0]*w2.z + xp[2]*w2.w;
    float sv3 = cv2[1]*w3.x + cv2[2]*w3.y + cv2[3]*w3.z + xp[3]*w3.w;
    f32x4 u4;
    u4[0] = sv0 / (1.f + __expf(-sv0));
    u4[1] = sv1 / (1.f + __expf(-sv1));
    u4[2] = sv2 / (1.f + __expf(-sv2));
    u4[3] = sv3 / (1.f + __expf(-sv3));
    *(f32x4*)(u_ws + idx) = u4;
    f32x4 n0, n1, n2;
    n0[0] = cv0[1]; n0[1] = cv0[2]; n0[2] = xp[0]; n0[3] = cv1[0];
    n1[0] = cv1[1]; n1[1] = xp[1];  n1[2] = cv1[3]; n1[3] = cv2[0];
    n2[0] = xp[2];  n2[1] = cv2[2]; n2[2] = cv2[3]; n2[3] = xp[3];
    float* on = ncs + idx * 3;
    *(f32x4*)(on)     = n0;
    *(f32x4*)(on + 4) = n1;
    *(f32x4*)(on + 8) = n2;
    // dA = exp(A); A flat is exactly 524288 elems too
    f32x4 a4 = *(const f32x4*)(A + idx);
    f32x4 e4;
    e4[0] = __expf(a4[0]); e4[1] = __expf(a4[1]);
    e4[2] = __expf(a4[2]); e4[3] = __expf(a4[3]);
    *(f32x4*)(dAe + idx) = e4;
  }
  grid.sync();

  // Phase 3: SSM stream (R1-proven body, dA from table)
  {
    const int chunk = bid >> 7;
    const int b = bid & 127;
    const int d0 = chunk * 1024 + tid * 4;
    f32x4 u4  = *(const f32x4*)(u_ws + (size_t)b * DI + d0);
    f32x4 dp4 = *(const f32x4*)(Dp + d0);
    float accx = dp4[0]*u4[0], accy = dp4[1]*u4[1];
    float accz = dp4[2]*u4[2], accw = dp4[3]*u4[3];
    const float* sp = ssm + (size_t)b * NS * DI + d0;
    float* op = nss + (size_t)b * NS * DI + d0;
#pragma unroll 4
    for (int n = 0; n < NS; ++n) {
      f32x4 a4 = *(const f32x4*)(dAe + (size_t)n * DI + d0);   // L2-resident
      f32x4 s4 = __builtin_nontemporal_load((const f32x4*)(sp + (size_t)n * DI));
      float bn = Bp[n], cn = Cp[n];
      f32x4 ns4;
      ns4[0] = a4[0] * s4[0] + bn * u4[0];
      ns4[1] = a4[1] * s4[1] + bn * u4[1];
      ns4[2] = a4[2] * s4[2] + bn * u4[2];
      ns4[3] = a4[3] * s4[3] + bn * u4[3];
      __builtin_nontemporal_store(ns4, (f32x4*)(op + (size_t)n * DI));
      accx += cn * ns4[0]; accy += cn * ns4[1];
      accz += cn * ns4[2]; accw += cn * ns4[3];
    }
    f32x4 r; r[0] = accx; r[1] = accy; r[2] = accz; r[3] = accw;
    *(f32x4*)(y_in + (size_t)b * DI + d0) = r;
  }
  grid.sync();

  // Phase 4: GEMM2 (y_in @ W_out.T) -> part2, NSPLIT=8 (64 nblk x 8 ks)
  gemm_phase<DM, DI, 8>(y_in, W_out, part2, As, Bs, bid, tid);
  grid.sync();

  // Phase 5: combine2 -> y_t
  {
    const int t = bid * NTHREADS + tid;     // 0..131071
    const int idx = t * 2;                  // 262144 elems
    const int j = idx & (DM - 1);
    float2 v = *(const float2*)(b_out + j);
#pragma unroll
    for (int s = 0; s < 8; ++s) {
      float2 p = *(const float2*)(part2 + (size_t)s * (BB * DM) + idx);
      v.x += p.x; v.y += p.y;
    }
    *(float2*)(y_t + idx) = v;
  }
}

// ---------------- Fallback standalone kernels (R1 exact) ----------------
template<int N, int K, int NSPLIT>
__global__ __launch_bounds__(256) void gemm_bf16(
    const float* __restrict__ Xg, const float* __restrict__ Wg,
    float* __restrict__ part) {
  __shared__ __hip_bfloat16 As[128][40];
  __shared__ __hip_bfloat16 Bs[32][40];
  gemm_phase<N, K, NSPLIT>(Xg, Wg, part, As, Bs, blockIdx.x, threadIdx.x);
}

__global__ __launch_bounds__(256) void combine1(
    const float* __restrict__ part, const float* __restrict__ b_in,
    const float* __restrict__ conv_state, const float* __restrict__ conv_weight,
    float* __restrict__ u_ws, float* __restrict__ ncs) {
  int idx = blockIdx.x * 256 + threadIdx.x;
  int d = idx & (DI - 1);
  float xp = b_in[d];
#pragma unroll
  for (int s = 0; s < 4; ++s) xp += part[(size_t)s * (BB * DI) + idx];
  const float* cs = conv_state + (size_t)idx * 3;
  float4 w4 = *(const float4*)(conv_weight + d * 4);
  float c0 = cs[0], c1 = cs[1], c2 = cs[2];
  float sv = c0 * w4.x + c1 * w4.y + c2 * w4.z + xp * w4.w;
  float uu = sv / (1.f + __expf(-sv));
  u_ws[idx] = uu;
  float* o = ncs + (size_t)idx * 3;
  o[0] = c1; o[1] = c2; o[2] = xp;
}

__global__ __launch_bounds__(256) void ssm_kernel(
    const float* __restrict__ ssm, const float* __restrict__ A,
    const float* __restrict__ Bp, const float* __restrict__ Cp,
    const float* __restrict__ Dp, const float* __restrict__ u,
    float* __restrict__ nss, float* __restrict__ y_in) {
  const int chunk = blockIdx.x >> 7;
  const int b = blockIdx.x & 127;
  const int d0 = chunk * 1024 + threadIdx.x * 4;
  f32x4 u4  = *(const f32x4*)(u + (size_t)b * DI + d0);
  f32x4 dp4 = *(const f32x4*)(Dp + d0);
  float accx = dp4[0]*u4[0], accy = dp4[1]*u4[1];
  float accz = dp4[2]*u4[2], accw = dp4[3]*u4[3];
  const float* sp = ssm + (size_t)b * NS * DI + d0;
  float* op = nss + (size_t)b * NS * DI + d0;
#pragma unroll 4
  for (int n = 0; n < NS; ++n) {
    f32x4 a4 = *(const f32x4*)(A + (size_t)n * DI + d0);
    f32x4 s4 = __builtin_nontemporal_load((const f32x4*)(sp + (size_t)n * DI));
    float bn = Bp[n], cn = Cp[n];
    f32x4 ns4;
    ns4[0] = __expf(a4[0]) * s4[0] + bn * u4[0];
    ns4[1] = __expf(a4[1]) * s4[1] + bn * u4[1];
    ns4[2] = __expf(a4[2]) * s4[2] + bn * u4[2];
    ns4[3] = __expf(a4[3]) * s4[3] + bn * u4[3];
    __builtin_nontemporal_store(ns4, (f32x4*)(op + (size_t)n * DI));
    accx += cn * ns4[0]; accy += cn * ns4[1];
    accz += cn * ns4[2]; accw += cn * ns4[3];
  }
  f32x4 r; r[0] = accx; r[1] = accy; r[2] = accz; r[3] = accw;
  *(f32x4*)(y_in + (size_t)b * DI + d0) = r;
}

__global__ __launch_bounds__(256) void combine2(
    const float* __restrict__ part, const float* __restrict__ b_out,
    float* __restrict__ y_t) {
  int idx = blockIdx.x * 256 + threadIdx.x;
  int j = idx & (DM - 1);
  float v = b_out[j];
#pragma unroll
  for (int s = 0; s < 8; ++s) v += part[(size_t)s * (BB * DM) + idx];
  y_t[idx] = v;
}

extern "C" void kernel_launch(void* const* d_in, const int* in_sizes, int n_in,
                              void* d_out, int out_size, void* d_ws, size_t ws_size,
                              hipStream_t stream) {
  const float* x_t         = (const float*)d_in[0];
  const float* conv_state  = (const float*)d_in[1];
  const float* ssm_state   = (const float*)d_in[2];
  const float* W_in        = (const float*)d_in[3];
  const float* b_in        = (const float*)d_in[4];
  const float* conv_weight = (const float*)d_in[5];
  const float* A           = (const float*)d_in[6];
  const float* Bp          = (const float*)d_in[7];
  const float* Cp          = (const float*)d_in[8];
  const float* Dp          = (const float*)d_in[9];
  const float* W_out       = (const float*)d_in[10];
  const float* b_out       = (const float*)d_in[11];

  float* y_t = (float*)d_out;                       // [128][2048]
  float* ncs = y_t + (size_t)BB * DM;               // [128][4096][3]
  float* nss = ncs + (size_t)BB * DI * 3;           // [128][128][4096]

  float* ws = (float*)d_ws;
  const size_t P1 = 4u * BB * DI;     // 2,097,152 floats
  const size_t P2 = 8u * BB * DM;     // 2,097,152 floats
  const size_t UV = (size_t)BB * DI;  // 524,288
  const size_t DA = (size_t)NS * DI;  // 524,288

  // Workspace layout for the fused path
  float *part1, *part2, *u_ws, *y_in, *dAe;
  bool ws_big = ws_size >= (P1 + P2 + 2 * UV + DA) * sizeof(float);
  if (ws_big) {
    part1 = ws; part2 = part1 + P1; u_ws = part2 + P2;
    y_in = u_ws + UV; dAe = y_in + UV;
  } else {
    part1 = nss;   // consumed in phase 2 before phase 3 writes nss
    part2 = ws; u_ws = part2 + P2; y_in = u_ws + UV; dAe = y_in + UV;
  }

  bool fused_ok = false;
  if (ws_size >= (P2 + 2 * UV + DA) * sizeof(float)) {
    int dev = 0, coop = 0;
    hipGetDevice(&dev);
    hipDeviceGetAttribute(&coop, hipDeviceAttributeCooperativeLaunch, dev);
    if (coop) {
      void* args[] = {
        (void*)&x_t, (void*)&conv_state, (void*)&ssm_state,
        (void*)&W_in, (void*)&b_in, (void*)&conv_weight,
        (void*)&A, (void*)&Bp, (void*)&Cp, (void*)&Dp,
        (void*)&W_out, (void*)&b_out,
        (void*)&y_t, (void*)&ncs, (void*)&nss,
        (void*)&part1, (void*)&part2, (void*)&u_ws, (void*)&y_in, (void*)&dAe
      };
      hipError_t e = hipLaunchCooperativeKernel(
          (const void*)fused_all, dim3(512), dim3(NTHREADS), args, 0, stream);
      fused_ok = (e == hipSuccess);
    }
  }
  if (fused_ok) return;

  // Fallback: R1 exact 5-kernel path
  {
    float* p1 = nss;  // consumed by combine1 before ssm writes nss
    float* p2 = ws;
    float* uw = p2 + P2;
    float* yi = uw + UV;
    gemm_bf16<DI, DM, 4><<<dim3(512), dim3(256), 0, stream>>>(x_t, W_in, p1);
    combine1<<<dim3(2048), dim3(256), 0, stream>>>(p1, b_in, conv_state,
                                                   conv_weight, uw, ncs);
    ssm_kernel<<<dim3(512), dim3(256), 0, stream>>>(ssm_state, A, Bp, Cp, Dp,
                                                    uw, nss, yi);
    gemm_bf16<DM, DI, 8><<<dim3(512), dim3(256), 0, stream>>>(yi, W_out, p2);
    combine2<<<dim3(1024), dim3(256), 0, stream>>>(p2, b_out, y_t);
  }
}

// Round 6
// 148.010 us; speedup vs baseline: 2.6955x; 2.6955x over previous
//
#include <hip/hip_runtime.h>
#include <hip/hip_bf16.h>

#define DI 4096
#define DM 2048
#define NS 128
#define BB 128

typedef __attribute__((ext_vector_type(8))) short bf16x8;
typedef __attribute__((ext_vector_type(4))) float f32x4;

__device__ __forceinline__ unsigned short f2bf(float f) {
  union { __hip_bfloat16 h; unsigned short u; } c;
  c.h = __float2bfloat16(f);
  return c.u;
}

// Load float4, optionally summing NSUM streams at stride `str`.
template<int NSUM>
__device__ __forceinline__ float4 ldsum(const float* p, size_t str) {
  float4 a = *(const float4*)p;
#pragma unroll
  for (int j = 1; j < NSUM; ++j) {
    float4 t = *(const float4*)(p + (size_t)j * str);
    a.x += t.x; a.y += t.y; a.z += t.z; a.w += t.w;
  }
  return a;
}

// C[b][n] = sum_k X[b][k]*W[n][k]; K split NSPLIT ways into partials.
// X may be NSUM summed streams (stride xstr). R1-proven body otherwise.
// Block tile M=128 x N=32, K-step 32. 4 waves as 2(M) x 2(N).
template<int N, int K, int NSPLIT, int NSUM>
__global__ __launch_bounds__(256) void gemm_bf16(
    const float* __restrict__ Xg, size_t xstr,
    const float* __restrict__ Wg, float* __restrict__ part) {
  constexpr int NBLKS = N / 32;
  constexpr int KS = K / NSPLIT;
  constexpr int NSTEPS = KS / 32;
  const int nblk = blockIdx.x % NBLKS;
  const int ks   = blockIdx.x / NBLKS;
  const int kbase = ks * KS;
  const int tid = threadIdx.x;
  const int lane = tid & 63;
  const int wid = tid >> 6;
  const int wr = wid & 1;
  const int wc = wid >> 1;
  const int r16 = lane & 15;
  const int kb = lane >> 4;

  __shared__ __hip_bfloat16 As[128][40];  // padded: no bank conflicts
  __shared__ __hip_bfloat16 Bs[32][40];

  const int arow = tid >> 3;
  const int seg  = tid & 7;

  f32x4 acc[4] = { {0,0,0,0}, {0,0,0,0}, {0,0,0,0}, {0,0,0,0} };

  const float* aG = Xg + (size_t)arow * K + kbase + seg * 4;
  const float* bG = Wg + (size_t)(nblk * 32 + arow) * K + kbase + seg * 4;

  float4 pa0 = ldsum<NSUM>(aG + 0 * 32 * K, xstr);
  float4 pa1 = ldsum<NSUM>(aG + 1 * 32 * K, xstr);
  float4 pa2 = ldsum<NSUM>(aG + 2 * 32 * K, xstr);
  float4 pa3 = ldsum<NSUM>(aG + 3 * 32 * K, xstr);
  float4 pb  = *(const float4*)(bG);

  for (int step = 0; step < NSTEPS; ++step) {
    if (step) __syncthreads();
    {
      ushort4 h;
      h.x = f2bf(pa0.x); h.y = f2bf(pa0.y); h.z = f2bf(pa0.z); h.w = f2bf(pa0.w);
      *(ushort4*)&As[arow +  0][seg * 4] = h;
      h.x = f2bf(pa1.x); h.y = f2bf(pa1.y); h.z = f2bf(pa1.z); h.w = f2bf(pa1.w);
      *(ushort4*)&As[arow + 32][seg * 4] = h;
      h.x = f2bf(pa2.x); h.y = f2bf(pa2.y); h.z = f2bf(pa2.z); h.w = f2bf(pa2.w);
      *(ushort4*)&As[arow + 64][seg * 4] = h;
      h.x = f2bf(pa3.x); h.y = f2bf(pa3.y); h.z = f2bf(pa3.z); h.w = f2bf(pa3.w);
      *(ushort4*)&As[arow + 96][seg * 4] = h;
      h.x = f2bf(pb.x);  h.y = f2bf(pb.y);  h.z = f2bf(pb.z);  h.w = f2bf(pb.w);
      *(ushort4*)&Bs[arow][seg * 4] = h;
    }
    if (step + 1 < NSTEPS) {  // prefetch next K-step
      const int o = (step + 1) * 32;
      pa0 = ldsum<NSUM>(aG + o + 0 * 32 * K, xstr);
      pa1 = ldsum<NSUM>(aG + o + 1 * 32 * K, xstr);
      pa2 = ldsum<NSUM>(aG + o + 2 * 32 * K, xstr);
      pa3 = ldsum<NSUM>(aG + o + 3 * 32 * K, xstr);
      pb  = *(const float4*)(bG + o);
    }
    __syncthreads();
    bf16x8 bv = *(const bf16x8*)&Bs[wc * 16 + r16][kb * 8];
#pragma unroll
    for (int m = 0; m < 4; ++m) {
      bf16x8 av = *(const bf16x8*)&As[wr * 64 + m * 16 + r16][kb * 8];
      acc[m] = __builtin_amdgcn_mfma_f32_16x16x32_bf16(av, bv, acc[m], 0, 0, 0);
    }
  }

  // C/D layout: col = lane&15, row = (lane>>4)*4 + reg   [guide §3, verified]
  const int ncol = nblk * 32 + wc * 16 + r16;
#pragma unroll
  for (int m = 0; m < 4; ++m) {
#pragma unroll
    for (int r = 0; r < 4; ++r) {
      int brow = wr * 64 + m * 16 + kb * 4 + r;
      part[(size_t)(ks * 128 + brow) * N + ncol] = acc[m][r];
    }
  }
}

// Sum GEMM1 partials + bias, then conv + silu. Emits u and new_conv_state.
// (R1 exact)
__global__ __launch_bounds__(256) void combine1(
    const float* __restrict__ part, const float* __restrict__ b_in,
    const float* __restrict__ conv_state, const float* __restrict__ conv_weight,
    float* __restrict__ u_ws, float* __restrict__ ncs) {
  int idx = blockIdx.x * 256 + threadIdx.x;   // b*DI + d
  int d = idx & (DI - 1);
  float xp = b_in[d];
#pragma unroll
  for (int s = 0; s < 4; ++s) xp += part[(size_t)s * (BB * DI) + idx];
  const float* cs = conv_state + (size_t)idx * 3;
  float4 w4 = *(const float4*)(conv_weight + d * 4);
  float c0 = cs[0], c1 = cs[1], c2 = cs[2];
  float sv = c0 * w4.x + c1 * w4.y + c2 * w4.z + xp * w4.w;
  float uu = sv / (1.f + __expf(-sv));
  u_ws[idx] = uu;
  float* o = ncs + (size_t)idx * 3;
  o[0] = c1; o[1] = c2; o[2] = xp;
}

// Contiguous-stream SSM: block = (b, n-half). 1024 threads cover a FULL
// 16KB row per n; each block streams 64 rows = 1MB contiguous read+write.
// 512 blocks x 16 waves = 32 waves/CU. yq holds 2 partials of y_inner
// (q0 carries the D*u term); GEMM2 sums them during A-staging.
__global__ __launch_bounds__(1024) void ssm_contig(
    const float* __restrict__ ssm, const float* __restrict__ A,
    const float* __restrict__ Bp, const float* __restrict__ Cp,
    const float* __restrict__ Dp, const float* __restrict__ u,
    float* __restrict__ nss, float* __restrict__ yq) {
  const int b = blockIdx.x & 127;
  const int q = blockIdx.x >> 7;          // n-half: 0 or 1
  const int n0 = q * (NS / 2);
  const int d0 = threadIdx.x * 4;         // 0..4092, full row
  f32x4 u4 = *(const f32x4*)(u + (size_t)b * DI + d0);
  float accx, accy, accz, accw;
  if (q == 0) {
    f32x4 dp4 = *(const f32x4*)(Dp + d0);
    accx = dp4[0]*u4[0]; accy = dp4[1]*u4[1];
    accz = dp4[2]*u4[2]; accw = dp4[3]*u4[3];
  } else {
    accx = accy = accz = accw = 0.f;
  }
  const float* sp = ssm + ((size_t)b * NS + n0) * DI + d0;
  float* op = nss + ((size_t)b * NS + n0) * DI + d0;
  const float* ap = A + (size_t)n0 * DI + d0;
#pragma unroll 4
  for (int i = 0; i < NS / 2; ++i) {
    f32x4 a4 = *(const f32x4*)(ap + (size_t)i * DI);     // L2-resident
    f32x4 s4 = __builtin_nontemporal_load((const f32x4*)(sp + (size_t)i * DI));
    float bn = Bp[n0 + i], cn = Cp[n0 + i];
    f32x4 ns4;
    ns4[0] = __expf(a4[0]) * s4[0] + bn * u4[0];
    ns4[1] = __expf(a4[1]) * s4[1] + bn * u4[1];
    ns4[2] = __expf(a4[2]) * s4[2] + bn * u4[2];
    ns4[3] = __expf(a4[3]) * s4[3] + bn * u4[3];
    __builtin_nontemporal_store(ns4, (f32x4*)(op + (size_t)i * DI));
    accx += cn * ns4[0]; accy += cn * ns4[1];
    accz += cn * ns4[2]; accw += cn * ns4[3];
  }
  f32x4 r; r[0] = accx; r[1] = accy; r[2] = accz; r[3] = accw;
  *(f32x4*)(yq + (size_t)q * (BB * DI) + (size_t)b * DI + d0) = r;
}

// (fallback only) R1 ssm
__global__ __launch_bounds__(256) void ssm_kernel(
    const float* __restrict__ ssm, const float* __restrict__ A,
    const float* __restrict__ Bp, const float* __restrict__ Cp,
    const float* __restrict__ Dp, const float* __restrict__ u,
    float* __restrict__ nss, float* __restrict__ y_in) {
  const int chunk = blockIdx.x >> 7;
  const int b = blockIdx.x & 127;
  const int d0 = chunk * 1024 + threadIdx.x * 4;
  f32x4 u4  = *(const f32x4*)(u + (size_t)b * DI + d0);
  f32x4 dp4 = *(const f32x4*)(Dp + d0);
  float accx = dp4[0]*u4[0], accy = dp4[1]*u4[1];
  float accz = dp4[2]*u4[2], accw = dp4[3]*u4[3];
  const float* sp = ssm + (size_t)b * NS * DI + d0;
  float* op = nss + (size_t)b * NS * DI + d0;
#pragma unroll 4
  for (int n = 0; n < NS; ++n) {
    f32x4 a4 = *(const f32x4*)(A + (size_t)n * DI + d0);
    f32x4 s4 = __builtin_nontemporal_load((const f32x4*)(sp + (size_t)n * DI));
    float bn = Bp[n], cn = Cp[n];
    f32x4 ns4;
    ns4[0] = __expf(a4[0]) * s4[0] + bn * u4[0];
    ns4[1] = __expf(a4[1]) * s4[1] + bn * u4[1];
    ns4[2] = __expf(a4[2]) * s4[2] + bn * u4[2];
    ns4[3] = __expf(a4[3]) * s4[3] + bn * u4[3];
    __builtin_nontemporal_store(ns4, (f32x4*)(op + (size_t)n * DI));
    accx += cn * ns4[0]; accy += cn * ns4[1];
    accz += cn * ns4[2]; accw += cn * ns4[3];
  }
  f32x4 r; r[0] = accx; r[1] = accy; r[2] = accz; r[3] = accw;
  *(f32x4*)(y_in + (size_t)b * DI + d0) = r;
}

template<int NSPL>
__global__ __launch_bounds__(256) void combine2(
    const float* __restrict__ part, const float* __restrict__ b_out,
    float* __restrict__ y_t) {
  int idx = blockIdx.x * 256 + threadIdx.x;  // b*DM + j
  int j = idx & (DM - 1);
  float v = b_out[j];
#pragma unroll
  for (int s = 0; s < NSPL; ++s) v += part[(size_t)s * (BB * DM) + idx];
  y_t[idx] = v;
}

extern "C" void kernel_launch(void* const* d_in, const int* in_sizes, int n_in,
                              void* d_out, int out_size, void* d_ws, size_t ws_size,
                              hipStream_t stream) {
  const float* x_t         = (const float*)d_in[0];
  const float* conv_state  = (const float*)d_in[1];
  const float* ssm_state   = (const float*)d_in[2];
  const float* W_in        = (const float*)d_in[3];
  const float* b_in        = (const float*)d_in[4];
  const float* conv_weight = (const float*)d_in[5];
  const float* A           = (const float*)d_in[6];
  const float* Bp          = (const float*)d_in[7];
  const float* Cp          = (const float*)d_in[8];
  const float* Dp          = (const float*)d_in[9];
  const float* W_out       = (const float*)d_in[10];
  const float* b_out       = (const float*)d_in[11];

  float* y_t = (float*)d_out;                       // [128][2048]
  float* ncs = y_t + (size_t)BB * DM;               // [128][4096][3]
  float* nss = ncs + (size_t)BB * DI * 3;           // [128][128][4096]

  float* ws = (float*)d_ws;
  const size_t P2 = 8u * BB * DM;     // 2,097,152 floats (8 MB)
  const size_t UV = (size_t)BB * DI;  // 524,288 floats (2 MB)

  if (ws_size >= (P2 + 2 * UV) * sizeof(float)) {
    // Main path. Layout (12 MB):
    //   part2 = ws[0 .. P2)      (written by GEMM2, read by combine2)
    //   u_ws  = ws[0 .. UV)      ALIASES part2's first split: u is written by
    //                            combine1, read by ssm_contig, and dead before
    //                            GEMM2 writes part2. Safe by stream ordering.
    //   yq    = ws[P2 .. P2+2UV) (2 n-half partials of y_inner)
    //   part1 = nss region       (consumed by combine1 before ssm writes nss)
    float* part1 = nss;
    float* part2 = ws;
    float* u_ws  = ws;
    float* yq    = ws + P2;

    gemm_bf16<DI, DM, 4, 1><<<dim3(512), dim3(256), 0, stream>>>(
        x_t, 0, W_in, part1);
    combine1<<<dim3(2048), dim3(256), 0, stream>>>(
        part1, b_in, conv_state, conv_weight, u_ws, ncs);
    ssm_contig<<<dim3(256), dim3(1024), 0, stream>>>(
        ssm_state, A, Bp, Cp, Dp, u_ws, nss, yq);
    gemm_bf16<DM, DI, 8, 2><<<dim3(512), dim3(256), 0, stream>>>(
        yq, UV, W_out, part2);
    combine2<8><<<dim3(1024), dim3(256), 0, stream>>>(part2, b_out, y_t);
  } else {
    // Fallback: R1 exact 5-kernel path (12 MB would also be needed here;
    // kept for structural safety).
    float* p1 = nss;
    float* p2 = ws;
    float* uw = p2 + P2;
    float* yi = uw + UV;
    gemm_bf16<DI, DM, 4, 1><<<dim3(512), dim3(256), 0, stream>>>(
        x_t, 0, W_in, p1);
    combine1<<<dim3(2048), dim3(256), 0, stream>>>(p1, b_in, conv_state,
                                                   conv_weight, uw, ncs);
    ssm_kernel<<<dim3(512), dim3(256), 0, stream>>>(ssm_state, A, Bp, Cp, Dp,
                                                    uw, nss, yi);
    gemm_bf16<DM, DI, 8, 1><<<dim3(512), dim3(256), 0, stream>>>(
        yi, 0, W_out, p2);
    combine2<8><<<dim3(1024), dim3(256), 0, stream>>>(p2, b_out, y_t);
  }
}

// Round 7
// 129.772 us; speedup vs baseline: 3.0743x; 1.1405x over previous
//
#include <hip/hip_runtime.h>
#include <hip/hip_bf16.h>

#define DI 4096
#define DM 2048
#define NS 128
#define BB 128

typedef __attribute__((ext_vector_type(8))) short bf16x8;
typedef __attribute__((ext_vector_type(4))) float f32x4;

__device__ __forceinline__ unsigned short f2bf(float f) {
  union { __hip_bfloat16 h; unsigned short u; } c;
  c.h = __float2bfloat16(f);
  return c.u;
}

// C[b][n] = sum_k X[b][k] * W[n][k], K split NSPLIT ways into partials.
// Block tile: M=128 x N=32, K-step 32. 4 waves as 2(M) x 2(N).
// 2-deep ping-pong prefetch: loads issued 2 K-steps ahead so ~2 steps of
// compute+barrier (~300-600cy) cover HBM latency; 1-deep left ~550cy stalls
// at the vmcnt drain before each LDS write.
template<int N, int K, int NSPLIT>
__global__ __launch_bounds__(256) void gemm_bf16(
    const float* __restrict__ Xg, const float* __restrict__ Wg,
    float* __restrict__ part) {
  constexpr int NBLKS = N / 32;
  constexpr int KS = K / NSPLIT;     // K range per block
  constexpr int NSTEPS = KS / 32;    // 16 for both GEMMs (even)
  static_assert(NSTEPS % 2 == 0, "2-unrolled pipeline needs even NSTEPS");
  const int nblk = blockIdx.x % NBLKS;
  const int ks   = blockIdx.x / NBLKS;
  const int kbase = ks * KS;
  const int tid = threadIdx.x;
  const int lane = tid & 63;
  const int wid = tid >> 6;
  const int wr = wid & 1;            // M half (64 rows each)
  const int wc = wid >> 1;           // N half (16 cols each)
  const int r16 = lane & 15;
  const int kb = lane >> 4;

  __shared__ __hip_bfloat16 As[128][40];  // padded: no bank conflicts
  __shared__ __hip_bfloat16 Bs[32][40];

  const int arow = tid >> 3;   // 0..31
  const int seg  = tid & 7;    // 0..7 (float4 segment within 32-wide K slice)

  f32x4 acc[4] = { {0,0,0,0}, {0,0,0,0}, {0,0,0,0}, {0,0,0,0} };

  const float* aG = Xg + (size_t)arow * K + kbase + seg * 4;
  const float* bG = Wg + (size_t)(nblk * 32 + arow) * K + kbase + seg * 4;

  // Ping-pong register sets (named, compile-time indexed — rule #20)
  float4 qa0, qa1, qa2, qa3, qb;   // set A
  float4 ra0, ra1, ra2, ra3, rb;   // set B
  qa0 = *(const float4*)(aG + 0 * 32 * K);
  qa1 = *(const float4*)(aG + 1 * 32 * K);
  qa2 = *(const float4*)(aG + 2 * 32 * K);
  qa3 = *(const float4*)(aG + 3 * 32 * K);
  qb  = *(const float4*)(bG);
  ra0 = *(const float4*)(aG + 32 + 0 * 32 * K);
  ra1 = *(const float4*)(aG + 32 + 1 * 32 * K);
  ra2 = *(const float4*)(aG + 32 + 2 * 32 * K);
  ra3 = *(const float4*)(aG + 32 + 3 * 32 * K);
  rb  = *(const float4*)(bG + 32);

  for (int s = 0; s < NSTEPS; s += 2) {
    // ---- even step: stage set A, prefetch s+2 into A ----
    if (s) __syncthreads();
    {
      ushort4 h;
      h.x = f2bf(qa0.x); h.y = f2bf(qa0.y); h.z = f2bf(qa0.z); h.w = f2bf(qa0.w);
      *(ushort4*)&As[arow +  0][seg * 4] = h;
      h.x = f2bf(qa1.x); h.y = f2bf(qa1.y); h.z = f2bf(qa1.z); h.w = f2bf(qa1.w);
      *(ushort4*)&As[arow + 32][seg * 4] = h;
      h.x = f2bf(qa2.x); h.y = f2bf(qa2.y); h.z = f2bf(qa2.z); h.w = f2bf(qa2.w);
      *(ushort4*)&As[arow + 64][seg * 4] = h;
      h.x = f2bf(qa3.x); h.y = f2bf(qa3.y); h.z = f2bf(qa3.z); h.w = f2bf(qa3.w);
      *(ushort4*)&As[arow + 96][seg * 4] = h;
      h.x = f2bf(qb.x);  h.y = f2bf(qb.y);  h.z = f2bf(qb.z);  h.w = f2bf(qb.w);
      *(ushort4*)&Bs[arow][seg * 4] = h;
    }
    if (s + 2 < NSTEPS) {
      const int o = (s + 2) * 32;
      qa0 = *(const float4*)(aG + o + 0 * 32 * K);
      qa1 = *(const float4*)(aG + o + 1 * 32 * K);
      qa2 = *(const float4*)(aG + o + 2 * 32 * K);
      qa3 = *(const float4*)(aG + o + 3 * 32 * K);
      qb  = *(const float4*)(bG + o);
    }
    __syncthreads();
    {
      bf16x8 bv = *(const bf16x8*)&Bs[wc * 16 + r16][kb * 8];
#pragma unroll
      for (int m = 0; m < 4; ++m) {
        bf16x8 av = *(const bf16x8*)&As[wr * 64 + m * 16 + r16][kb * 8];
        acc[m] = __builtin_amdgcn_mfma_f32_16x16x32_bf16(av, bv, acc[m], 0, 0, 0);
      }
    }
    // ---- odd step: stage set B, prefetch s+3 into B ----
    __syncthreads();
    {
      ushort4 h;
      h.x = f2bf(ra0.x); h.y = f2bf(ra0.y); h.z = f2bf(ra0.z); h.w = f2bf(ra0.w);
      *(ushort4*)&As[arow +  0][seg * 4] = h;
      h.x = f2bf(ra1.x); h.y = f2bf(ra1.y); h.z = f2bf(ra1.z); h.w = f2bf(ra1.w);
      *(ushort4*)&As[arow + 32][seg * 4] = h;
      h.x = f2bf(ra2.x); h.y = f2bf(ra2.y); h.z = f2bf(ra2.z); h.w = f2bf(ra2.w);
      *(ushort4*)&As[arow + 64][seg * 4] = h;
      h.x = f2bf(ra3.x); h.y = f2bf(ra3.y); h.z = f2bf(ra3.z); h.w = f2bf(ra3.w);
      *(ushort4*)&As[arow + 96][seg * 4] = h;
      h.x = f2bf(rb.x);  h.y = f2bf(rb.y);  h.z = f2bf(rb.z);  h.w = f2bf(rb.w);
      *(ushort4*)&Bs[arow][seg * 4] = h;
    }
    if (s + 3 < NSTEPS) {
      const int o = (s + 3) * 32;
      ra0 = *(const float4*)(aG + o + 0 * 32 * K);
      ra1 = *(const float4*)(aG + o + 1 * 32 * K);
      ra2 = *(const float4*)(aG + o + 2 * 32 * K);
      ra3 = *(const float4*)(aG + o + 3 * 32 * K);
      rb  = *(const float4*)(bG + o);
    }
    __syncthreads();
    {
      bf16x8 bv = *(const bf16x8*)&Bs[wc * 16 + r16][kb * 8];
#pragma unroll
      for (int m = 0; m < 4; ++m) {
        bf16x8 av = *(const bf16x8*)&As[wr * 64 + m * 16 + r16][kb * 8];
        acc[m] = __builtin_amdgcn_mfma_f32_16x16x32_bf16(av, bv, acc[m], 0, 0, 0);
      }
    }
  }

  // C/D layout: col = lane&15, row = (lane>>4)*4 + reg   [guide §3, verified]
  const int ncol = nblk * 32 + wc * 16 + r16;
#pragma unroll
  for (int m = 0; m < 4; ++m) {
#pragma unroll
    for (int r = 0; r < 4; ++r) {
      int brow = wr * 64 + m * 16 + kb * 4 + r;
      part[(size_t)(ks * 128 + brow) * N + ncol] = acc[m][r];
    }
  }
}

// Sum GEMM1 partials + bias, then conv + silu. Emits u and new_conv_state.
// (R1 exact)
__global__ __launch_bounds__(256) void combine1(
    const float* __restrict__ part, const float* __restrict__ b_in,
    const float* __restrict__ conv_state, const float* __restrict__ conv_weight,
    float* __restrict__ u_ws, float* __restrict__ ncs) {
  int idx = blockIdx.x * 256 + threadIdx.x;   // b*DI + d, < 524288
  int d = idx & (DI - 1);
  float xp = b_in[d];
#pragma unroll
  for (int s = 0; s < 4; ++s) xp += part[(size_t)s * (BB * DI) + idx];
  const float* cs = conv_state + (size_t)idx * 3;
  float4 w4 = *(const float4*)(conv_weight + d * 4);
  float c0 = cs[0], c1 = cs[1], c2 = cs[2];
  float sv = c0 * w4.x + c1 * w4.y + c2 * w4.z + xp * w4.w;
  float uu = sv / (1.f + __expf(-sv));
  u_ws[idx] = uu;
  float* o = ncs + (size_t)idx * 3;
  o[0] = c1; o[1] = c2; o[2] = xp;
}

// Streaming SSM (R1 exact): new_ssm = exp(A)*ssm + B*u ;
// y_in = sum_n C*new_ssm + D*u
__global__ __launch_bounds__(256) void ssm_kernel(
    const float* __restrict__ ssm, const float* __restrict__ A,
    const float* __restrict__ Bp, const float* __restrict__ Cp,
    const float* __restrict__ Dp, const float* __restrict__ u,
    float* __restrict__ nss, float* __restrict__ y_in) {
  const int chunk = blockIdx.x >> 7;   // 0..3 (d-chunk of 1024)
  const int b = blockIdx.x & 127;
  const int d0 = chunk * 1024 + threadIdx.x * 4;
  f32x4 u4  = *(const f32x4*)(u + (size_t)b * DI + d0);
  f32x4 dp4 = *(const f32x4*)(Dp + d0);
  float accx = dp4[0]*u4[0], accy = dp4[1]*u4[1];
  float accz = dp4[2]*u4[2], accw = dp4[3]*u4[3];
  const float* sp = ssm + (size_t)b * NS * DI + d0;
  float* op = nss + (size_t)b * NS * DI + d0;
#pragma unroll 4
  for (int n = 0; n < NS; ++n) {
    f32x4 a4 = *(const f32x4*)(A + (size_t)n * DI + d0);            // L2-resident
    f32x4 s4 = __builtin_nontemporal_load((const f32x4*)(sp + (size_t)n * DI));
    float bn = Bp[n], cn = Cp[n];
    f32x4 ns4;
    ns4[0] = __expf(a4[0]) * s4[0] + bn * u4[0];
    ns4[1] = __expf(a4[1]) * s4[1] + bn * u4[1];
    ns4[2] = __expf(a4[2]) * s4[2] + bn * u4[2];
    ns4[3] = __expf(a4[3]) * s4[3] + bn * u4[3];
    __builtin_nontemporal_store(ns4, (f32x4*)(op + (size_t)n * DI));
    accx += cn * ns4[0]; accy += cn * ns4[1];
    accz += cn * ns4[2]; accw += cn * ns4[3];
  }
  f32x4 r; r[0] = accx; r[1] = accy; r[2] = accz; r[3] = accw;
  *(f32x4*)(y_in + (size_t)b * DI + d0) = r;
}

__global__ __launch_bounds__(256) void combine2(
    const float* __restrict__ part, const float* __restrict__ b_out,
    float* __restrict__ y_t) {
  int idx = blockIdx.x * 256 + threadIdx.x;  // b*DM + j, < 262144
  int j = idx & (DM - 1);
  float v = b_out[j];
#pragma unroll
  for (int s = 0; s < 8; ++s) v += part[(size_t)s * (BB * DM) + idx];
  y_t[idx] = v;
}

extern "C" void kernel_launch(void* const* d_in, const int* in_sizes, int n_in,
                              void* d_out, int out_size, void* d_ws, size_t ws_size,
                              hipStream_t stream) {
  const float* x_t         = (const float*)d_in[0];
  const float* conv_state  = (const float*)d_in[1];
  const float* ssm_state   = (const float*)d_in[2];
  const float* W_in        = (const float*)d_in[3];
  const float* b_in        = (const float*)d_in[4];
  const float* conv_weight = (const float*)d_in[5];
  const float* A           = (const float*)d_in[6];
  const float* Bp          = (const float*)d_in[7];
  const float* Cp          = (const float*)d_in[8];
  const float* Dp          = (const float*)d_in[9];
  const float* W_out       = (const float*)d_in[10];
  const float* b_out       = (const float*)d_in[11];

  float* y_t = (float*)d_out;                       // [128][2048]
  float* ncs = y_t + (size_t)BB * DM;               // [128][4096][3]
  float* nss = ncs + (size_t)BB * DI * 3;           // [128][128][4096]

  float* ws = (float*)d_ws;
  const size_t P1 = 4u * BB * DI;   // 2,097,152 floats
  const size_t P2 = 8u * BB * DM;   // 2,097,152 floats
  const size_t UV = (size_t)BB * DI;
  float *part1, *part2, *u_ws, *y_in;
  if (ws_size >= (P1 + P2 + 2 * UV) * sizeof(float)) {
    part1 = ws; part2 = part1 + P1; u_ws = part2 + P2; y_in = u_ws + UV;
  } else {
    // GEMM1 partials are fully consumed before ssm_kernel writes nss region
    part1 = nss;
    part2 = ws; u_ws = part2 + P2; y_in = u_ws + UV;
  }

  gemm_bf16<DI, DM, 4><<<dim3(512), dim3(256), 0, stream>>>(x_t, W_in, part1);
  combine1<<<dim3(2048), dim3(256), 0, stream>>>(part1, b_in, conv_state,
                                                 conv_weight, u_ws, ncs);
  ssm_kernel<<<dim3(512), dim3(256), 0, stream>>>(ssm_state, A, Bp, Cp, Dp,
                                                  u_ws, nss, y_in);
  gemm_bf16<DM, DI, 8><<<dim3(512), dim3(256), 0, stream>>>(y_in, W_out, part2);
  combine2<<<dim3(1024), dim3(256), 0, stream>>>(part2, b_out, y_t);
}